// Round 1
// baseline (140.472 us; speedup 1.0000x reference)
//
#include <hip/hip_runtime.h>
#include <math.h>

#define BS    512
#define NBIN  2048
#define CAP   1024
#define VOCAB 128000
#define NROW  256
#define TOPC  63

__global__ __launch_bounds__(BS) void sampler_kernel(
    const float* __restrict__ logits,
    const float* __restrict__ temps,
    const float* __restrict__ topps,
    const float* __restrict__ topks,
    const float* __restrict__ noise,
    float* __restrict__ out)   // [NROW tokens as f32][NROW*VOCAB scaled f32]
{
  const int row = blockIdx.x;
  const int tid = threadIdx.x;

  __shared__ unsigned int hist[NBIN];
  __shared__ float red_m[BS], red_s[BS];
  __shared__ float cv[CAP];
  __shared__ int   ci[CAP];
  __shared__ float sv[CAP];
  __shared__ int   si[CAP];
  __shared__ unsigned int nc_sh;
  __shared__ int bsel_sh;

  const float temp   = temps[row];
  const float safe_t = (temp == 0.0f) ? 1.0f : temp;

  for (int i = tid; i < NBIN; i += BS) hist[i] = 0u;
  if (tid == 0) nc_sh = 0u;
  __syncthreads();

  const float4* __restrict__ lg4 =
      reinterpret_cast<const float4*>(logits + (size_t)row * VOCAB);
  float4* __restrict__ out4 =
      reinterpret_cast<float4*>(out + NROW + (size_t)row * VOCAB);

  // ---- Phase A: scaled write + online softmax + histogram ----
  float m_loc = -INFINITY, s_loc = 0.0f;
  for (int j = tid; j < VOCAB / 4; j += BS) {
    float4 x = lg4[j];
    float4 s;
    s.x = x.x / safe_t; s.y = x.y / safe_t;
    s.z = x.z / safe_t; s.w = x.w / safe_t;
    out4[j] = s;
    float vv[4] = {s.x, s.y, s.z, s.w};
    #pragma unroll
    for (int c = 0; c < 4; ++c) {
      float v = vv[c];
      if (v > m_loc) { s_loc = s_loc * __expf(m_loc - v) + 1.0f; m_loc = v; }
      else           { s_loc += __expf(v - m_loc); }
      int bin = (int)((v + 64.0f) * 16.0f);
      bin = bin < 0 ? 0 : (bin > NBIN - 1 ? NBIN - 1 : bin);
      atomicAdd(&hist[bin], 1u);
    }
  }

  // ---- block reduce (m, sumexp) ----
  red_m[tid] = m_loc; red_s[tid] = s_loc;
  __syncthreads();
  for (int off = BS / 2; off > 0; off >>= 1) {
    if (tid < off) {
      float m1 = red_m[tid], m2 = red_m[tid + off];
      float s1 = red_s[tid], s2 = red_s[tid + off];
      float mm = fmaxf(m1, m2);
      red_m[tid] = mm;
      red_s[tid] = s1 * __expf(m1 - mm) + s2 * __expf(m2 - mm);
    }
    __syncthreads();
  }
  const float row_m = red_m[0];
  const float row_S = red_s[0];

  // ---- find histogram-bin threshold covering top-63 ----
  if (tid == 0) {
    unsigned int acc = 0; int b = NBIN - 1;
    for (; b > 0; --b) { acc += hist[b]; if (acc >= (unsigned)TOPC) break; }
    bsel_sh = b;
  }
  __syncthreads();
  const int bsel = bsel_sh;

  // ---- Phase B: re-read, collect candidates (bin >= bsel) ----
  for (int j = tid; j < VOCAB / 4; j += BS) {
    float4 x = lg4[j];
    float vv[4];
    vv[0] = x.x / safe_t; vv[1] = x.y / safe_t;
    vv[2] = x.z / safe_t; vv[3] = x.w / safe_t;
    #pragma unroll
    for (int c = 0; c < 4; ++c) {
      float v = vv[c];
      int bin = (int)((v + 64.0f) * 16.0f);
      bin = bin < 0 ? 0 : (bin > NBIN - 1 ? NBIN - 1 : bin);
      if (bin >= bsel) {
        unsigned int p = atomicAdd(&nc_sh, 1u);
        if (p < CAP) { cv[p] = v; ci[p] = j * 4 + c; }
      }
    }
  }
  __syncthreads();
  const int n = (nc_sh < (unsigned)CAP) ? (int)nc_sh : CAP;

  // ---- sort candidates by (value desc, index asc) via rank ----
  for (int i = tid; i < n; i += BS) {
    float vi = cv[i]; int xi = ci[i];
    int r = 0;
    for (int j2 = 0; j2 < n; ++j2) {
      float vj = cv[j2]; int xj = ci[j2];
      r += (int)((vj > vi) || (vj == vi && xj < xi));
    }
    sv[r] = vi; si[r] = xi;
  }
  __syncthreads();

  // ---- Phase D: joint top-k/top-p mask + Gumbel-max sample ----
  if (tid == 0) {
    const float kk = topks[row];
    const float tp = topps[row];
    const float invS = 1.0f / row_S;
    const float* __restrict__ nrow = noise + (size_t)row * VOCAB;
    int lim = (n < TOPC) ? n : TOPC;
    float cdf = 0.0f, best = -INFINITY; int bestj = 0;
    for (int j = 0; j < lim; ++j) {
      float sp = expf(sv[j] - row_m) * invS;          // sorted prob
      if (((float)j < kk) && (cdf <= tp)) {           // joint keep mask
        float u = nrow[j];                            // noise at SORTED position
        float g = -logf(-logf(u));
        float sc = logf(sp) + g;
        if (sc > best) { best = sc; bestj = j; }      // strict > = first-max tie
      }
      cdf += sp;                                      // exclusive cumsum
    }
    int token = si[bestj];
    if (temp == 0.0f) token = si[0];                  // greedy fallback
    out[row] = (float)token;
  }
}

extern "C" void kernel_launch(void* const* d_in, const int* in_sizes, int n_in,
                              void* d_out, int out_size, void* d_ws, size_t ws_size,
                              hipStream_t stream) {
  const float* logits = (const float*)d_in[0];
  const float* temps  = (const float*)d_in[1];
  const float* topps  = (const float*)d_in[2];
  const float* topks  = (const float*)d_in[3];
  const float* noise  = (const float*)d_in[4];
  float* out = (float*)d_out;
  sampler_kernel<<<NROW, BS, 0, stream>>>(logits, temps, topps, topks, noise, out);
}